// Round 2
// baseline (59.241 us; speedup 1.0000x reference)
//
#include <hip/hip_runtime.h>
#include <hip/hip_bf16.h>

#define EPS 1e-5f

typedef _Float16 f16x8 __attribute__((ext_vector_type(8)));
typedef short short4v __attribute__((ext_vector_type(4)));
typedef short short8v __attribute__((ext_vector_type(8)));
typedef float f32x4 __attribute__((ext_vector_type(4)));

static __device__ __forceinline__ unsigned short f2h(float x) {
    _Float16 h = (_Float16)x;
    return *reinterpret_cast<unsigned short*>(&h);
}

// ---------------- Kernel 1: BN(q) + transpose (B,C,Nq) -> (B,Nq,C) fp16 ----------------
__global__ void bn_q_kernel(const float* __restrict__ q,
                            const float* __restrict__ qg, const float* __restrict__ qb,
                            const float* __restrict__ qm, const float* __restrict__ qv,
                            unsigned short* __restrict__ Qh) {
    __shared__ unsigned short lds[64][66];   // +2 pad: transpose without bank conflicts
    const int t = threadIdx.x;
    const int b = blockIdx.y;
    const int n0 = blockIdx.x * 64;
#pragma unroll
    for (int r = 0; r < 16; ++r) {
        int idx = r * 256 + t;
        int c = idx >> 6, n = idx & 63;          // consecutive lanes -> consecutive n (coalesced)
        float val = q[(b * 64 + c) * 4096 + n0 + n];
        float inv = qg[c] * rsqrtf(qv[c] + EPS);
        float bias = qb[c] - qm[c] * inv;
        lds[n][c] = f2h(val * inv + bias);
    }
    __syncthreads();
#pragma unroll
    for (int r = 0; r < 8; ++r) {
        int p = r * 256 + t;
        int n = p >> 5, c2 = p & 31;             // consecutive lanes -> consecutive c-pairs
        unsigned int u = *reinterpret_cast<const unsigned int*>(&lds[n][c2 * 2]);
        reinterpret_cast<unsigned int*>(Qh)[(b * 4096 + n0 + n) * 32 + c2] = u;
    }
}

// ------- Kernel 2: 1x1 convs (+BN fold for K): K (B,Nv,64) fp16, V^T (B,64,Nv) fp16 -------
__global__ void conv_kv_kernel(const float* __restrict__ v,
                               const float* __restrict__ k_w, const float* __restrict__ v_w,
                               const float* __restrict__ kg, const float* __restrict__ kbe,
                               const float* __restrict__ km, const float* __restrict__ kvv,
                               unsigned short* __restrict__ Kt, unsigned short* __restrict__ Vt) {
    __shared__ float kw_lds[128 * 64];  // [c][o], XOR swizzled
    __shared__ float vw_lds[128 * 64];
    const int t = threadIdx.x;
    const int b = blockIdx.y;
#pragma unroll
    for (int r = 0; r < 32; ++r) {
        int idx = r * 256 + t;                   // over 64*128, c fast (coalesced reads)
        int o = idx >> 7, c = idx & 127;
        float invk = kg[o] * rsqrtf(kvv[o] + EPS);
        int sw = c * 64 + (o ^ (c & 31));
        kw_lds[sw] = k_w[idx] * invk;            // fold BN scale into K weights
        vw_lds[sw] = v_w[idx];
    }
    const int o = t & 63, g = t >> 6;
    const int m0 = blockIdx.x * 32 + g * 8;
    float invk = kg[o] * rsqrtf(kvv[o] + EPS);
    float biask = kbe[o] - km[o] * invk;
    __syncthreads();
    float acck[8] = {0.f, 0.f, 0.f, 0.f, 0.f, 0.f, 0.f, 0.f};
    float accv[8] = {0.f, 0.f, 0.f, 0.f, 0.f, 0.f, 0.f, 0.f};
    for (int c = 0; c < 128; ++c) {
        float kw = kw_lds[c * 64 + (o ^ (c & 31))];
        float vw = vw_lds[c * 64 + (o ^ (c & 31))];
        const float4* vp = reinterpret_cast<const float4*>(&v[(size_t)(b * 128 + c) * 1024 + m0]);
        float4 v0 = vp[0], v1 = vp[1];
        acck[0] += kw * v0.x; acck[1] += kw * v0.y; acck[2] += kw * v0.z; acck[3] += kw * v0.w;
        acck[4] += kw * v1.x; acck[5] += kw * v1.y; acck[6] += kw * v1.z; acck[7] += kw * v1.w;
        accv[0] += vw * v0.x; accv[1] += vw * v0.y; accv[2] += vw * v0.z; accv[3] += vw * v0.w;
        accv[4] += vw * v1.x; accv[5] += vw * v1.y; accv[6] += vw * v1.z; accv[7] += vw * v1.w;
    }
#pragma unroll
    for (int j = 0; j < 8; ++j) {
        // K stored key-major (B, Nv, 64): lanes (o) coalesced per j
        Kt[(size_t)(b * 1024 + m0 + j) * 64 + o] = f2h(acck[j] + biask);
    }
    unsigned short vb[8];
#pragma unroll
    for (int j = 0; j < 8; ++j) vb[j] = f2h(accv[j]);
    // V^T stored (B, 64, Nv): one 16B store per thread
    *reinterpret_cast<short8v*>(&Vt[(size_t)(b * 64 + o) * 1024 + m0]) =
        *reinterpret_cast<const short8v*>(vb);
}

// ---------------- Kernel 3: flash attention, swapped-operand MFMA (fp16) ----------------
__global__ __launch_bounds__(256) void attn_kernel(const unsigned short* __restrict__ Qh,
                                                   const unsigned short* __restrict__ Kt,
                                                   const unsigned short* __restrict__ Vt,
                                                   float* __restrict__ out) {
    __shared__ unsigned short kTile[64 * 72];        // [key][c], row stride 72 (144B)
    __shared__ unsigned short vTile[64 * 72];        // [c][key]
    __shared__ unsigned short pTile[4 * 16 * 72];    // per-wave [qrow][key]
    const int t = threadIdx.x;
    const int w = t >> 6, lane = t & 63, g = lane >> 4, qr = lane & 15;
    const int b = blockIdx.y, n0 = blockIdx.x * 64;
    const int nq = n0 + w * 16 + qr;

    // Q B-fragments (col=qrow=lane&15, k=c contiguous): held in registers for whole KV loop
    const f16x8 qf0 = *reinterpret_cast<const f16x8*>(Qh + (size_t)(b * 4096 + nq) * 64 + g * 8);
    const f16x8 qf1 = *reinterpret_cast<const f16x8*>(Qh + (size_t)(b * 4096 + nq) * 64 + 32 + g * 8);

    f32x4 oacc[4];
#pragma unroll
    for (int cb = 0; cb < 4; ++cb) oacc[cb] = (f32x4){0.f, 0.f, 0.f, 0.f};
    float m_run = -3e38f, l_run = 0.f;

#pragma unroll 1
    for (int kt = 0; kt < 16; ++kt) {
        __syncthreads();  // previous iteration's tile reads done
#pragma unroll
        for (int r = 0; r < 2; ++r) {
            int id = r * 256 + t;
            int row = id >> 3, off = (id & 7) * 8;
            *reinterpret_cast<short8v*>(kTile + row * 72 + off) =
                *reinterpret_cast<const short8v*>(Kt + (size_t)(b * 1024 + kt * 64 + row) * 64 + off);
            *reinterpret_cast<short8v*>(vTile + row * 72 + off) =
                *reinterpret_cast<const short8v*>(Vt + (size_t)(b * 64 + row) * 1024 + kt * 64 + off);
        }
        __syncthreads();

        // S^T[key][qrow] = K · Q^T : D row=key(4g+i within 16-block), col=qrow
        f32x4 s[4];
#pragma unroll
        for (int kb = 0; kb < 4; ++kb) {
            f16x8 ka0 = *reinterpret_cast<const f16x8*>(kTile + (kb * 16 + qr) * 72 + g * 8);
            f16x8 ka1 = *reinterpret_cast<const f16x8*>(kTile + (kb * 16 + qr) * 72 + 32 + g * 8);
            f32x4 acc = {0.f, 0.f, 0.f, 0.f};
            acc = __builtin_amdgcn_mfma_f32_16x16x32_f16(ka0, qf0, acc, 0, 0, 0);
            acc = __builtin_amdgcn_mfma_f32_16x16x32_f16(ka1, qf1, acc, 0, 0, 0);
            s[kb] = acc;
        }

        // online softmax per q-row (= per lane column); row spread over lane-groups
        float tmax = -3e38f;
#pragma unroll
        for (int kb = 0; kb < 4; ++kb)
#pragma unroll
            for (int i = 0; i < 4; ++i) tmax = fmaxf(tmax, s[kb][i]);
        tmax = fmaxf(tmax, __shfl_xor(tmax, 16));
        tmax = fmaxf(tmax, __shfl_xor(tmax, 32));
        float mnew = fmaxf(m_run, tmax);
        float scale = __expf(m_run - mnew);
        float psum = 0.f;
        unsigned short pb[16];
#pragma unroll
        for (int kb = 0; kb < 4; ++kb)
#pragma unroll
            for (int i = 0; i < 4; ++i) {
                float p = __expf(s[kb][i] - mnew);
                psum += p;
                pb[kb * 4 + i] = f2h(p);
            }
        psum += __shfl_xor(psum, 16);
        psum += __shfl_xor(psum, 32);
        l_run = l_run * scale + psum;
        m_run = mnew;
#pragma unroll
        for (int cb = 0; cb < 4; ++cb) oacc[cb] = oacc[cb] * scale;

        // P -> per-wave LDS [qrow][key] (keys 16kb+4g..+3 contiguous per write)
#pragma unroll
        for (int kb = 0; kb < 4; ++kb) {
            short4v pk;
            pk[0] = (short)pb[kb * 4 + 0]; pk[1] = (short)pb[kb * 4 + 1];
            pk[2] = (short)pb[kb * 4 + 2]; pk[3] = (short)pb[kb * 4 + 3];
            *reinterpret_cast<short4v*>(pTile + (w * 16 + qr) * 72 + kb * 16 + g * 4) = pk;
        }
        // O^T += V^T · P^T  (per-wave pTile: wave-internal dependency, no barrier needed)
#pragma unroll
        for (int ch = 0; ch < 2; ++ch) {
            f16x8 pf = *reinterpret_cast<const f16x8*>(pTile + (w * 16 + qr) * 72 + ch * 32 + g * 8);
#pragma unroll
            for (int cb = 0; cb < 4; ++cb) {
                f16x8 vf = *reinterpret_cast<const f16x8*>(vTile + (cb * 16 + qr) * 72 + ch * 32 + g * 8);
                oacc[cb] = __builtin_amdgcn_mfma_f32_16x16x32_f16(vf, pf, oacc[cb], 0, 0, 0);
            }
        }
    }

    const float rl = 1.f / l_run;
#pragma unroll
    for (int cb = 0; cb < 4; ++cb)
#pragma unroll
        for (int i = 0; i < 4; ++i)
            out[(size_t)(b * 64 + cb * 16 + g * 4 + i) * 4096 + n0 + w * 16 + qr] = oacc[cb][i] * rl;
}

extern "C" void kernel_launch(void* const* d_in, const int* in_sizes, int n_in,
                              void* d_out, int out_size, void* d_ws, size_t ws_size,
                              hipStream_t stream) {
    const float* q   = (const float*)d_in[0];
    const float* v   = (const float*)d_in[1];
    const float* k_w = (const float*)d_in[2];
    const float* v_w = (const float*)d_in[3];
    const float* qg  = (const float*)d_in[4];
    const float* qb  = (const float*)d_in[5];
    const float* qm  = (const float*)d_in[6];
    const float* qv  = (const float*)d_in[7];
    const float* kg  = (const float*)d_in[8];
    const float* kbe = (const float*)d_in[9];
    const float* km  = (const float*)d_in[10];
    const float* kvv = (const float*)d_in[11];

    unsigned short* Qh = (unsigned short*)d_ws;            // 8*4096*64 fp16 = 4 MB
    unsigned short* Kt = Qh + (size_t)8 * 4096 * 64;       // 8*1024*64 fp16 = 1 MB
    unsigned short* Vt = Kt + (size_t)8 * 1024 * 64;       // 1 MB

    bn_q_kernel<<<dim3(64, 8), 256, 0, stream>>>(q, qg, qb, qm, qv, Qh);
    conv_kv_kernel<<<dim3(32, 8), 256, 0, stream>>>(v, k_w, v_w, kg, kbe, km, kvv, Kt, Vt);
    attn_kernel<<<dim3(64, 8), 256, 0, stream>>>(Qh, Kt, Vt, (float*)d_out);
}

// Round 4
// 48.763 us; speedup vs baseline: 1.2149x; 1.2149x over previous
//
#include <hip/hip_runtime.h>
#include <hip/hip_bf16.h>

#define EPS 1e-5f

typedef _Float16 f16x8 __attribute__((ext_vector_type(8)));
typedef short short4v __attribute__((ext_vector_type(4)));
typedef short short8v __attribute__((ext_vector_type(8)));
typedef float f32x4 __attribute__((ext_vector_type(4)));

static __device__ __forceinline__ unsigned short f2h(float x) {
    _Float16 h = (_Float16)x;
    return *reinterpret_cast<unsigned short*>(&h);
}

// ------- Kernel 1: 1x1 convs (+BN fold for K): K (B,Nv,64) fp16, V^T (B,64,Nv) fp16 -------
// grid (64, 8): each WG covers 16 m-positions -> 512 WGs, 2 waves/SIMD.
__global__ void conv_kv_kernel(const float* __restrict__ v,
                               const float* __restrict__ k_w, const float* __restrict__ v_w,
                               const float* __restrict__ kg, const float* __restrict__ kbe,
                               const float* __restrict__ km, const float* __restrict__ kvv,
                               unsigned short* __restrict__ Kt, unsigned short* __restrict__ Vt) {
    __shared__ float kw_lds[128 * 64];  // [c][o], XOR swizzled
    __shared__ float vw_lds[128 * 64];
    const int t = threadIdx.x;
    const int b = blockIdx.y;
#pragma unroll
    for (int r = 0; r < 32; ++r) {
        int idx = r * 256 + t;                   // over 64*128, c fast (coalesced reads)
        int o = idx >> 7, c = idx & 127;
        float invk = kg[o] * rsqrtf(kvv[o] + EPS);
        int sw = c * 64 + (o ^ (c & 31));
        kw_lds[sw] = k_w[idx] * invk;            // fold BN scale into K weights
        vw_lds[sw] = v_w[idx];
    }
    const int o = t & 63, g = t >> 6;
    const int m0 = blockIdx.x * 16 + g * 4;
    float invk = kg[o] * rsqrtf(kvv[o] + EPS);
    float biask = kbe[o] - km[o] * invk;
    __syncthreads();
    float acck[4] = {0.f, 0.f, 0.f, 0.f};
    float accv[4] = {0.f, 0.f, 0.f, 0.f};
    for (int c = 0; c < 128; ++c) {
        float kw = kw_lds[c * 64 + (o ^ (c & 31))];
        float vw = vw_lds[c * 64 + (o ^ (c & 31))];
        float4 v0 = *reinterpret_cast<const float4*>(&v[(size_t)(b * 128 + c) * 1024 + m0]);
        acck[0] += kw * v0.x; acck[1] += kw * v0.y; acck[2] += kw * v0.z; acck[3] += kw * v0.w;
        accv[0] += vw * v0.x; accv[1] += vw * v0.y; accv[2] += vw * v0.z; accv[3] += vw * v0.w;
    }
#pragma unroll
    for (int j = 0; j < 4; ++j)
        Kt[(size_t)(b * 1024 + m0 + j) * 64 + o] = f2h(acck[j] + biask);
    unsigned short vb[4];
#pragma unroll
    for (int j = 0; j < 4; ++j) vb[j] = f2h(accv[j]);
    *reinterpret_cast<short4v*>(&Vt[(size_t)(b * 64 + o) * 1024 + m0]) =
        *reinterpret_cast<const short4v*>(vb);
}

// ------- Kernel 2: fused BN(q) + flash attention, double-buffered staging -------
__global__ __launch_bounds__(256) void attn_kernel(const float* __restrict__ q,
                                                   const float* __restrict__ qg, const float* __restrict__ qb,
                                                   const float* __restrict__ qm, const float* __restrict__ qv,
                                                   const unsigned short* __restrict__ Kt,
                                                   const unsigned short* __restrict__ Vt,
                                                   float* __restrict__ out) {
    __shared__ unsigned short kT[2][64 * 72];        // [key][c], row stride 72 (2-way only)
    __shared__ unsigned short vT[2][64 * 72];        // [c][key]
    __shared__ unsigned short pT[4][16 * 72];        // per-wave [qrow][key]
    __shared__ float ib[128];                        // inv*log2e [64], bias*log2e [64]
    const int t = threadIdx.x;
    const int w = t >> 6, lane = t & 63, g = lane >> 4, qr = lane & 15;
    const int b = blockIdx.y, n0 = blockIdx.x * 64;
    const int nq = n0 + w * 16 + qr;

    // staging coords: pass r covers rows r*32 + (t>>3), 16B chunk (t&7)*8 elems
    const int r0 = t >> 3, r1 = 32 + (t >> 3), o0 = (t & 7) * 8;

    // issue tile-0 loads immediately (hide under BN/Q setup)
    short8v ka0 = *reinterpret_cast<const short8v*>(Kt + (size_t)(b * 1024 + r0) * 64 + o0);
    short8v ka1 = *reinterpret_cast<const short8v*>(Kt + (size_t)(b * 1024 + r1) * 64 + o0);
    short8v va0 = *reinterpret_cast<const short8v*>(Vt + (size_t)(b * 64 + r0) * 1024 + o0);
    short8v va1 = *reinterpret_cast<const short8v*>(Vt + (size_t)(b * 64 + r1) * 1024 + o0);

    if (t < 64) {
        float inv = qg[t] * rsqrtf(qv[t] + EPS);
        ib[t] = inv * 1.44269504f;                   // fold log2(e): softmax in base-2
        ib[64 + t] = (qb[t] - qm[t] * inv) * 1.44269504f;
    }
    __syncthreads();

    // Q B-fragments with fused BN (col=qrow=lane&15, k=c contiguous)
    f16x8 qf0, qf1;
#pragma unroll
    for (int j = 0; j < 8; ++j) {
        int c0 = g * 8 + j, c1 = 32 + g * 8 + j;
        float x0 = q[(size_t)(b * 64 + c0) * 4096 + nq];
        float x1 = q[(size_t)(b * 64 + c1) * 4096 + nq];
        qf0[j] = (_Float16)(x0 * ib[c0] + ib[64 + c0]);
        qf1[j] = (_Float16)(x1 * ib[c1] + ib[64 + c1]);
    }

    // write tile 0 into buffer 0
    *reinterpret_cast<short8v*>(&kT[0][r0 * 72 + o0]) = ka0;
    *reinterpret_cast<short8v*>(&kT[0][r1 * 72 + o0]) = ka1;
    *reinterpret_cast<short8v*>(&vT[0][r0 * 72 + o0]) = va0;
    *reinterpret_cast<short8v*>(&vT[0][r1 * 72 + o0]) = va1;

    f32x4 oacc[4];
#pragma unroll
    for (int cb = 0; cb < 4; ++cb) oacc[cb] = (f32x4){0.f, 0.f, 0.f, 0.f};
    float m_run = -1e30f, l_run = 0.f;
    int cur = 0;

#pragma unroll 1
    for (int kt = 0; kt < 16; ++kt) {
        __syncthreads();                              // buf[cur] staged by all waves
        // T14: issue next tile's global loads now; consumed after next barrier
        short8v kn0, kn1, vn0, vn1;
        if (kt < 15) {
            const unsigned short* Kp = Kt + (size_t)(b * 1024 + (kt + 1) * 64) * 64;
            const unsigned short* Vp = Vt + (size_t)(b * 64) * 1024 + (kt + 1) * 64;
            kn0 = *reinterpret_cast<const short8v*>(Kp + r0 * 64 + o0);
            kn1 = *reinterpret_cast<const short8v*>(Kp + r1 * 64 + o0);
            vn0 = *reinterpret_cast<const short8v*>(Vp + r0 * 1024 + o0);
            vn1 = *reinterpret_cast<const short8v*>(Vp + r1 * 1024 + o0);
        }
        const unsigned short* kTile = kT[cur];
        const unsigned short* vTile = vT[cur];

        // S^T[key][qrow] = K · Q^T (values pre-scaled by log2e)
        f32x4 s[4];
#pragma unroll
        for (int kb = 0; kb < 4; ++kb) {
            f16x8 kf0 = *reinterpret_cast<const f16x8*>(kTile + (kb * 16 + qr) * 72 + g * 8);
            f16x8 kf1 = *reinterpret_cast<const f16x8*>(kTile + (kb * 16 + qr) * 72 + 32 + g * 8);
            f32x4 acc = {0.f, 0.f, 0.f, 0.f};
            acc = __builtin_amdgcn_mfma_f32_16x16x32_f16(kf0, qf0, acc, 0, 0, 0);
            acc = __builtin_amdgcn_mfma_f32_16x16x32_f16(kf1, qf1, acc, 0, 0, 0);
            s[kb] = acc;
        }

        // online softmax (base-2) with defer-max
        float tmax = -1e30f;
#pragma unroll
        for (int kb = 0; kb < 4; ++kb)
#pragma unroll
            for (int i = 0; i < 4; ++i) tmax = fmaxf(tmax, s[kb][i]);
        tmax = fmaxf(tmax, __shfl_xor(tmax, 16));
        tmax = fmaxf(tmax, __shfl_xor(tmax, 32));
        float mnew = m_run;
        if (!__all(tmax - m_run <= 11.0f)) {          // rescale only on real max growth
            mnew = fmaxf(m_run, tmax);
            float sc = exp2f(m_run - mnew);
            l_run *= sc;
#pragma unroll
            for (int cb = 0; cb < 4; ++cb) oacc[cb] = oacc[cb] * sc;
            m_run = mnew;
        }
        float psum = 0.f;
        unsigned short pb[16];
#pragma unroll
        for (int kb = 0; kb < 4; ++kb)
#pragma unroll
            for (int i = 0; i < 4; ++i) {
                float p = exp2f(s[kb][i] - mnew);     // bounded by 2^11
                psum += p;
                pb[kb * 4 + i] = f2h(p);
            }
        psum += __shfl_xor(psum, 16);
        psum += __shfl_xor(psum, 32);
        l_run += psum;

        // P -> per-wave LDS, then O^T += V^T · P^T
#pragma unroll
        for (int kb = 0; kb < 4; ++kb) {
            short4v pk;
            pk[0] = (short)pb[kb * 4 + 0]; pk[1] = (short)pb[kb * 4 + 1];
            pk[2] = (short)pb[kb * 4 + 2]; pk[3] = (short)pb[kb * 4 + 3];
            *reinterpret_cast<short4v*>(&pT[w][qr * 72 + kb * 16 + g * 4]) = pk;
        }
#pragma unroll
        for (int ch = 0; ch < 2; ++ch) {
            f16x8 pf = *reinterpret_cast<const f16x8*>(&pT[w][qr * 72 + ch * 32 + g * 8]);
#pragma unroll
            for (int cb = 0; cb < 4; ++cb) {
                f16x8 vf = *reinterpret_cast<const f16x8*>(vTile + (cb * 16 + qr) * 72 + ch * 32 + g * 8);
                oacc[cb] = __builtin_amdgcn_mfma_f32_16x16x32_f16(vf, pf, oacc[cb], 0, 0, 0);
            }
        }
        __syncthreads();                              // all waves done reading buf[cur^1]
        if (kt < 15) {                                // land prefetched tile in other buffer
            *reinterpret_cast<short8v*>(&kT[cur ^ 1][r0 * 72 + o0]) = kn0;
            *reinterpret_cast<short8v*>(&kT[cur ^ 1][r1 * 72 + o0]) = kn1;
            *reinterpret_cast<short8v*>(&vT[cur ^ 1][r0 * 72 + o0]) = vn0;
            *reinterpret_cast<short8v*>(&vT[cur ^ 1][r1 * 72 + o0]) = vn1;
        }
        cur ^= 1;
    }

    const float rl = 1.f / l_run;
#pragma unroll
    for (int cb = 0; cb < 4; ++cb)
#pragma unroll
        for (int i = 0; i < 4; ++i)
            out[(size_t)(b * 64 + cb * 16 + g * 4 + i) * 4096 + n0 + w * 16 + qr] = oacc[cb][i] * rl;
}

extern "C" void kernel_launch(void* const* d_in, const int* in_sizes, int n_in,
                              void* d_out, int out_size, void* d_ws, size_t ws_size,
                              hipStream_t stream) {
    const float* q   = (const float*)d_in[0];
    const float* v   = (const float*)d_in[1];
    const float* k_w = (const float*)d_in[2];
    const float* v_w = (const float*)d_in[3];
    const float* qg  = (const float*)d_in[4];
    const float* qb  = (const float*)d_in[5];
    const float* qm  = (const float*)d_in[6];
    const float* qv  = (const float*)d_in[7];
    const float* kg  = (const float*)d_in[8];
    const float* kbe = (const float*)d_in[9];
    const float* km  = (const float*)d_in[10];
    const float* kvv = (const float*)d_in[11];

    unsigned short* Kt = (unsigned short*)d_ws;            // 8*1024*64 fp16 = 1 MB
    unsigned short* Vt = Kt + (size_t)8 * 1024 * 64;       // 1 MB

    conv_kv_kernel<<<dim3(64, 8), 256, 0, stream>>>(v, k_w, v_w, kg, kbe, km, kvv, Kt, Vt);
    attn_kernel<<<dim3(64, 8), 256, 0, stream>>>(q, qg, qb, qm, qv, Kt, Vt, (float*)d_out);
}